// Round 1
// baseline (10948.661 us; speedup 1.0000x reference)
//
#include <hip/hip_runtime.h>
#include <math.h>

#define EB 32

__device__ __forceinline__ float silu_f(float x) { return x / (1.0f + expf(-x)); }

// ---------------- K1: node GEMM: sc = A@Wskip, xup = A@Wup, xdown = A@Wdown ----
__global__ __launch_bounds__(256) void k_node_gemm(
    const float* __restrict__ A,
    const float* __restrict__ Wskip, const float* __restrict__ Wup, const float* __restrict__ Wdown,
    float* __restrict__ sc, float* __restrict__ xup, float* __restrict__ xdown, int N)
{
    __shared__ float As[64][129];
    const int t = threadIdx.x;
    const int n0 = blockIdx.x * 64;
    for (int i = t; i < 64 * 32; i += 256) {
        int r = i >> 5, c4 = i & 31;
        int n = n0 + r;
        float4 v = make_float4(0.f, 0.f, 0.f, 0.f);
        if (n < N) v = ((const float4*)(A + (size_t)n * 128))[c4];
        As[r][c4 * 4 + 0] = v.x; As[r][c4 * 4 + 1] = v.y;
        As[r][c4 * 4 + 2] = v.z; As[r][c4 * 4 + 3] = v.w;
    }
    __syncthreads();
    const int tc = t & 15, tr = t >> 4;
    const int col0 = blockIdx.y * 64 + tc * 4;   // global col in [0, 320)
    const float* W; float* dst; int ldw, wc, ldd;
    if (col0 < 128)      { W = Wskip; ldw = 128; wc = col0;       dst = sc;    ldd = 128; }
    else if (col0 < 256) { W = Wup;   ldw = 128; wc = col0 - 128; dst = xup;   ldd = 128; }
    else                 { W = Wdown; ldw = 64;  wc = col0 - 256; dst = xdown; ldd = 64;  }
    float acc[4][4] = {};
    for (int k = 0; k < 128; k++) {
        float4 wv = *(const float4*)(W + (size_t)k * ldw + wc);
        float wvv[4] = {wv.x, wv.y, wv.z, wv.w};
        float av[4];
        #pragma unroll
        for (int ii = 0; ii < 4; ii++) av[ii] = As[tr * 4 + ii][k];
        #pragma unroll
        for (int ii = 0; ii < 4; ii++)
            #pragma unroll
            for (int jj = 0; jj < 4; jj++)
                acc[ii][jj] = fmaf(av[ii], wvv[jj], acc[ii][jj]);
    }
    #pragma unroll
    for (int ii = 0; ii < 4; ii++) {
        int n = n0 + tr * 4 + ii;
        if (n < N)
            *(float4*)(dst + (size_t)n * ldd + wc) =
                make_float4(acc[ii][0], acc[ii][1], acc[ii][2], acc[ii][3]);
    }
}

// ---------------- K3: edge MLP + tensor product + atomic scatter ---------------
__global__ __launch_bounds__(256) void k_edge(
    const float* __restrict__ ef, const float* __restrict__ ea, const int* __restrict__ eidx,
    const float* __restrict__ xup, const float* __restrict__ xdown,
    const float* __restrict__ W0, const float* __restrict__ W1,
    const float* __restrict__ W2, const float* __restrict__ W3,
    float* __restrict__ msg, int E)
{
    __shared__ float bufA[EB][264];
    __shared__ float bufB[EB][264];
    __shared__ float yb[EB][16];
    __shared__ int sE[EB], rE[EB];
    const int t = threadIdx.x;
    const int e0 = blockIdx.x * EB;
    if (t < EB) {
        int e = e0 + t; if (e >= E) e = E - 1;
        sE[t] = eidx[e];
        rE[t] = eidx[E + e];
    }
    __syncthreads();
    for (int i = t; i < EB * 16; i += 256) {
        int e = i >> 4, m = i & 15;
        int ee = e0 + e; if (ee >= E) ee = E - 1;
        yb[e][m] = ea[(size_t)ee * 16 + m];
    }
    for (int i = t; i < EB * 136; i += 256) {
        int e = i / 136, c = i - e * 136;
        float v;
        if (c < 8) { int ee = e0 + e; if (ee >= E) ee = E - 1; v = ef[(size_t)ee * 8 + c]; }
        else if (c < 72) v = xdown[(size_t)sE[e] * 64 + (c - 8)];
        else             v = xdown[(size_t)rE[e] * 64 + (c - 72)];
        bufA[e][c] = v;
    }
    __syncthreads();
    const int eg = t >> 5, cg = t & 31;

    auto layer = [&](const float (*in)[264], float (*out)[264], const float* __restrict__ W,
                     int Kin, int Nout, int colBase, float scale, bool dosilu) {
        float acc[4][8] = {};
        const int j0 = colBase + cg * 8;
        for (int k = 0; k < Kin; k++) {
            float w[8];
            const float* wr = W + (size_t)k * Nout + j0;
            *(float4*)&w[0] = *(const float4*)wr;
            *(float4*)&w[4] = *(const float4*)(wr + 4);
            float a[4];
            #pragma unroll
            for (int ii = 0; ii < 4; ii++) a[ii] = in[eg * 4 + ii][k];
            #pragma unroll
            for (int ii = 0; ii < 4; ii++)
                #pragma unroll
                for (int jj = 0; jj < 8; jj++)
                    acc[ii][jj] = fmaf(a[ii], w[jj], acc[ii][jj]);
        }
        #pragma unroll
        for (int ii = 0; ii < 4; ii++)
            #pragma unroll
            for (int jj = 0; jj < 8; jj++) {
                float x = acc[ii][jj] * scale;
                if (dosilu) x = silu_f(x);
                out[eg * 4 + ii][cg * 8 + jj] = x;
            }
    };

    const float CGT[4] = {1.0f, 0.57735026919f, 0.44721359550f, 0.37796447301f};

    auto tp_half = [&](const float (*tw)[264], int lbase) {
        const int e = t >> 3, sub = t & 7;
        if (e0 + e >= E) return;
        const int s = sE[e], r = rE[e];
        const float* xs = xup + (size_t)s * 128;
        float* mrow = msg + (size_t)r * 2048;
        #pragma unroll
        for (int li = 0; li < 2; li++) {
            const int l = lbase + li;
            const int d = 2 * l + 1;
            const int yoff = l * l;          // OFFS = l^2 : 0,1,4,9
            const int moff = 128 * (l * l);  // 0,128,512,1152
            const float cgl = CGT[l];
            for (int ci = 0; ci < 16; ci++) {
                int c = sub * 16 + ci;
                float u = tw[e][li * 128 + c] * xs[c] * cgl;
                float* mp = mrow + moff + c * d;
                const float* yv = &yb[e][yoff];
                for (int m = 0; m < d; m++)
                    atomicAdd(&mp[m], u * yv[m]);
            }
        }
    };

    constexpr float S0 = 0.085749292571254f; // 1/sqrt(136)
    layer(bufA, bufB, W0, 136, 256, 0, S0, true);
    __syncthreads();
    layer(bufB, bufA, W1, 256, 256, 0, 0.0625f, true);
    __syncthreads();
    layer(bufA, bufB, W2, 256, 256, 0, 0.0625f, true);
    __syncthreads();
    layer(bufB, bufA, W3, 256, 512, 0, 0.0625f, false);   // tp_w cols 0..255 (l=0,1)
    __syncthreads();
    tp_half(bufA, 0);
    __syncthreads();
    layer(bufB, bufA, W3, 256, 512, 256, 0.0625f, false); // tp_w cols 256..511 (l=2,3)
    __syncthreads();
    tp_half(bufA, 2);
}

// ---------------- K4: in-place per-node W_out transform ------------------------
__global__ __launch_bounds__(128) void k_out(
    float* __restrict__ buf, const float* __restrict__ Wout, int N)
{
    __shared__ float ms[8][2056];
    const int t = threadIdx.x;
    const int n0 = blockIdx.x * 8;
    for (int i = t; i < 8 * 512; i += 128) {
        int rr = i >> 9, c4 = i & 511;
        int n = n0 + rr;
        float4 v = make_float4(0.f, 0.f, 0.f, 0.f);
        if (n < N) v = ((const float4*)(buf + (size_t)n * 2048))[c4];
        ((float4*)&ms[rr][0])[c4] = v;
    }
    __syncthreads();
    const int tk = t & 15, tn = t >> 4;
    const int n = n0 + tn;
    float acc[8][16] = {};
    for (int c = 0; c < 128; c++) {
        float mv[16];
        mv[0] = ms[tn][c];
        #pragma unroll
        for (int m = 0; m < 3; m++) mv[1 + m] = ms[tn][128 + c * 3 + m];
        #pragma unroll
        for (int m = 0; m < 5; m++) mv[4 + m] = ms[tn][512 + c * 5 + m];
        #pragma unroll
        for (int m = 0; m < 7; m++) mv[9 + m] = ms[tn][1152 + c * 7 + m];
        #pragma unroll
        for (int i = 0; i < 8; i++) {
            const int k = tk + 16 * i;
            const float w0 = Wout[(size_t)c * 128 + k];
            const float w1 = Wout[16384 + (size_t)c * 128 + k];
            const float w2 = Wout[32768 + (size_t)c * 128 + k];
            const float w3 = Wout[49152 + (size_t)c * 128 + k];
            acc[i][0] = fmaf(w0, mv[0], acc[i][0]);
            #pragma unroll
            for (int m = 0; m < 3; m++) acc[i][1 + m] = fmaf(w1, mv[1 + m], acc[i][1 + m]);
            #pragma unroll
            for (int m = 0; m < 5; m++) acc[i][4 + m] = fmaf(w2, mv[4 + m], acc[i][4 + m]);
            #pragma unroll
            for (int m = 0; m < 7; m++) acc[i][9 + m] = fmaf(w3, mv[9 + m], acc[i][9 + m]);
        }
    }
    if (n < N) {
        #pragma unroll
        for (int i = 0; i < 8; i++) {
            const int k = tk + 16 * i;
            float* op = buf + (size_t)n * 2048 + k * 16;
            #pragma unroll
            for (int q = 0; q < 4; q++) {
                float4 v = make_float4(acc[i][q * 4 + 0] * 0.1f, acc[i][q * 4 + 1] * 0.1f,
                                       acc[i][q * 4 + 2] * 0.1f, acc[i][q * 4 + 3] * 0.1f);
                *(float4*)(op + q * 4) = v;
            }
        }
    }
}

extern "C" void kernel_launch(void* const* d_in, const int* in_sizes, int n_in,
                              void* d_out, int out_size, void* d_ws, size_t ws_size,
                              hipStream_t stream)
{
    const float* node_feats = (const float*)d_in[1];
    const float* edge_attrs = (const float*)d_in[2];
    const float* edge_feats = (const float*)d_in[3];
    const int*   edge_index = (const int*)d_in[4];
    const float* W_up   = (const float*)d_in[5];
    const float* W_down = (const float*)d_in[6];
    const float* W_skip = (const float*)d_in[7];
    const float* W_fc0  = (const float*)d_in[8];
    const float* W_fc1  = (const float*)d_in[9];
    const float* W_fc2  = (const float*)d_in[10];
    const float* W_fc3  = (const float*)d_in[11];
    const float* W_out  = (const float*)d_in[12];
    const int N = in_sizes[1] / 128;
    const int E = in_sizes[3] / 8;

    float* out = (float*)d_out;                  // first N*2048 floats: message -> out (in place)
    float* sc  = out + (size_t)N * 2048;
    float* xup   = (float*)d_ws;
    float* xdown = xup + (size_t)N * 128;

    hipMemsetAsync(out, 0, (size_t)N * 2048 * sizeof(float), stream);

    dim3 g1((N + 63) / 64, 5);
    k_node_gemm<<<g1, 256, 0, stream>>>(node_feats, W_skip, W_up, W_down, sc, xup, xdown, N);

    k_edge<<<(E + EB - 1) / EB, 256, 0, stream>>>(edge_feats, edge_attrs, edge_index,
                                                  xup, xdown, W_fc0, W_fc1, W_fc2, W_fc3,
                                                  out, E);

    k_out<<<(N + 7) / 8, 128, 0, stream>>>(out, W_out, N);
}

// Round 2
// 1436.199 us; speedup vs baseline: 7.6234x; 7.6234x over previous
//
#include <hip/hip_runtime.h>
#include <math.h>

#define EB 32

__device__ __forceinline__ float silu_f(float x) { return x / (1.0f + expf(-x)); }

// ---------------- K1: node GEMM: sc = A@Wskip, xup = A@Wup, xdown = A@Wdown ----
__global__ __launch_bounds__(256) void k_node_gemm(
    const float* __restrict__ A,
    const float* __restrict__ Wskip, const float* __restrict__ Wup, const float* __restrict__ Wdown,
    float* __restrict__ sc, float* __restrict__ xup, float* __restrict__ xdown, int N)
{
    __shared__ float As[64][129];
    const int t = threadIdx.x;
    const int n0 = blockIdx.x * 64;
    for (int i = t; i < 64 * 32; i += 256) {
        int r = i >> 5, c4 = i & 31;
        int n = n0 + r;
        float4 v = make_float4(0.f, 0.f, 0.f, 0.f);
        if (n < N) v = ((const float4*)(A + (size_t)n * 128))[c4];
        As[r][c4 * 4 + 0] = v.x; As[r][c4 * 4 + 1] = v.y;
        As[r][c4 * 4 + 2] = v.z; As[r][c4 * 4 + 3] = v.w;
    }
    __syncthreads();
    const int tc = t & 15, tr = t >> 4;
    const int col0 = blockIdx.y * 64 + tc * 4;   // global col in [0, 320)
    const float* W; float* dst; int ldw, wc, ldd;
    if (col0 < 128)      { W = Wskip; ldw = 128; wc = col0;       dst = sc;    ldd = 128; }
    else if (col0 < 256) { W = Wup;   ldw = 128; wc = col0 - 128; dst = xup;   ldd = 128; }
    else                 { W = Wdown; ldw = 64;  wc = col0 - 256; dst = xdown; ldd = 64;  }
    float acc[4][4] = {};
    for (int k = 0; k < 128; k++) {
        float4 wv = *(const float4*)(W + (size_t)k * ldw + wc);
        float wvv[4] = {wv.x, wv.y, wv.z, wv.w};
        float av[4];
        #pragma unroll
        for (int ii = 0; ii < 4; ii++) av[ii] = As[tr * 4 + ii][k];
        #pragma unroll
        for (int ii = 0; ii < 4; ii++)
            #pragma unroll
            for (int jj = 0; jj < 4; jj++)
                acc[ii][jj] = fmaf(av[ii], wvv[jj], acc[ii][jj]);
    }
    #pragma unroll
    for (int ii = 0; ii < 4; ii++) {
        int n = n0 + tr * 4 + ii;
        if (n < N)
            *(float4*)(dst + (size_t)n * ldd + wc) =
                make_float4(acc[ii][0], acc[ii][1], acc[ii][2], acc[ii][3]);
    }
}

// ---------------- K2: edge MLP -> tp_w (chunk) --------------------------------
__global__ __launch_bounds__(256) void k_mlp(
    const float* __restrict__ ef, const int* __restrict__ eidx,
    const float* __restrict__ xdown,
    const float* __restrict__ W0, const float* __restrict__ W1,
    const float* __restrict__ W2, const float* __restrict__ W3,
    float* __restrict__ tp_w, int E, int eLo, int eHi)
{
    __shared__ float bufA[EB][264];
    __shared__ float bufB[EB][264];
    __shared__ int sE[EB], rE[EB];
    const int t = threadIdx.x;
    const int e0 = eLo + blockIdx.x * EB;
    if (t < EB) {
        int e = e0 + t; if (e >= E) e = E - 1;
        sE[t] = eidx[e];
        rE[t] = eidx[E + e];
    }
    __syncthreads();
    for (int i = t; i < EB * 136; i += 256) {
        int e = i / 136, c = i - e * 136;
        float v;
        if (c < 8) { int ee = e0 + e; if (ee >= E) ee = E - 1; v = ef[(size_t)ee * 8 + c]; }
        else if (c < 72) v = xdown[(size_t)sE[e] * 64 + (c - 8)];
        else             v = xdown[(size_t)rE[e] * 64 + (c - 72)];
        bufA[e][c] = v;
    }
    __syncthreads();
    const int eg = t >> 5, cg = t & 31;

    auto layer = [&](const float (*in)[264], float (*out)[264], const float* __restrict__ W,
                     int Kin, int Nout, float scale) {
        float acc[4][8] = {};
        const int j0 = cg * 8;
        for (int k = 0; k < Kin; k++) {
            float w[8];
            const float* wr = W + (size_t)k * Nout + j0;
            *(float4*)&w[0] = *(const float4*)wr;
            *(float4*)&w[4] = *(const float4*)(wr + 4);
            float a[4];
            #pragma unroll
            for (int ii = 0; ii < 4; ii++) a[ii] = in[eg * 4 + ii][k];
            #pragma unroll
            for (int ii = 0; ii < 4; ii++)
                #pragma unroll
                for (int jj = 0; jj < 8; jj++)
                    acc[ii][jj] = fmaf(a[ii], w[jj], acc[ii][jj]);
        }
        #pragma unroll
        for (int ii = 0; ii < 4; ii++)
            #pragma unroll
            for (int jj = 0; jj < 8; jj++)
                out[eg * 4 + ii][j0 + jj] = silu_f(acc[ii][jj] * scale);
    };

    auto layer_out = [&](const float (*in)[264], const float* __restrict__ W, int colBase) {
        float acc[4][8] = {};
        const int j0 = colBase + cg * 8;
        for (int k = 0; k < 256; k++) {
            float w[8];
            const float* wr = W + (size_t)k * 512 + j0;
            *(float4*)&w[0] = *(const float4*)wr;
            *(float4*)&w[4] = *(const float4*)(wr + 4);
            float a[4];
            #pragma unroll
            for (int ii = 0; ii < 4; ii++) a[ii] = in[eg * 4 + ii][k];
            #pragma unroll
            for (int ii = 0; ii < 4; ii++)
                #pragma unroll
                for (int jj = 0; jj < 8; jj++)
                    acc[ii][jj] = fmaf(a[ii], w[jj], acc[ii][jj]);
        }
        #pragma unroll
        for (int ii = 0; ii < 4; ii++) {
            int e = e0 + eg * 4 + ii;
            if (e < eHi) {
                float* dst = tp_w + (size_t)(e - eLo) * 512 + j0;
                #pragma unroll
                for (int q = 0; q < 2; q++) {
                    float4 v = make_float4(acc[ii][q*4+0] * 0.0625f, acc[ii][q*4+1] * 0.0625f,
                                           acc[ii][q*4+2] * 0.0625f, acc[ii][q*4+3] * 0.0625f);
                    *(float4*)(dst + q * 4) = v;
                }
            }
        }
    };

    constexpr float S0 = 0.085749292571254f; // 1/sqrt(136)
    layer(bufA, bufB, W0, 136, 256, S0);
    __syncthreads();
    layer(bufB, bufA, W1, 256, 256, 0.0625f);
    __syncthreads();
    layer(bufA, bufB, W2, 256, 256, 0.0625f);
    __syncthreads();
    layer_out(bufB, W3, 0);
    layer_out(bufB, W3, 256);
}

// ---------------- CSR construction --------------------------------------------
__global__ __launch_bounds__(256) void k_hist(const int* __restrict__ recv, int* __restrict__ deg, int E)
{
    int e = blockIdx.x * 256 + threadIdx.x;
    if (e < E) atomicAdd(&deg[recv[e]], 1);
}

__global__ __launch_bounds__(1024) void k_scan(const int* __restrict__ deg, int* __restrict__ rowptr, int N)
{
    __shared__ int sdata[1024];
    __shared__ int carry;
    const int t = threadIdx.x;
    if (t == 0) carry = 0;
    __syncthreads();
    for (int base = 0; base < N; base += 1024) {
        int i = base + t;
        int v = (i < N) ? deg[i] : 0;
        sdata[t] = v;
        __syncthreads();
        for (int off = 1; off < 1024; off <<= 1) {
            int x = (t >= off) ? sdata[t - off] : 0;
            __syncthreads();
            sdata[t] += x;
            __syncthreads();
        }
        if (i < N) rowptr[i] = carry + sdata[t] - v;
        __syncthreads();
        if (t == 0) carry += sdata[1023];
        __syncthreads();
    }
    if (t == 0) rowptr[N] = carry;
}

__global__ __launch_bounds__(256) void k_scatter(const int* __restrict__ recv,
    const int* __restrict__ rowptr, int* __restrict__ fill, int* __restrict__ perm, int E)
{
    int e = blockIdx.x * 256 + threadIdx.x;
    if (e < E) {
        int r = recv[e];
        int pos = rowptr[r] + atomicAdd(&fill[r], 1);
        perm[pos] = e;
    }
}

__global__ __launch_bounds__(256) void k_sortlists(int* __restrict__ perm, const int* __restrict__ rowptr, int N)
{
    int n = blockIdx.x * 256 + threadIdx.x;
    if (n >= N) return;
    int lo = rowptr[n], hi = rowptr[n + 1];
    for (int i = lo + 1; i < hi; i++) {
        int key = perm[i];
        int j = i - 1;
        while (j >= lo && perm[j] > key) { perm[j + 1] = perm[j]; j--; }
        perm[j + 1] = key;
    }
}

// ---------------- K3: per-node gather + tensor product ------------------------
__global__ __launch_bounds__(256) void k_gather(
    const float* __restrict__ tp_w, const float* __restrict__ xup, const float* __restrict__ ea,
    const int* __restrict__ eidx, const int* __restrict__ perm, const int* __restrict__ rowptr,
    float* __restrict__ msg, int E, int eLo, int eHi, int storeMode)
{
    const int n = blockIdx.x;
    const int lo = rowptr[n], hi = rowptr[n + 1];
    const int t = threadIdx.x;
    const int c = t & 127, half = t >> 7;
    constexpr float CG1 = 0.57735026919f, CG2 = 0.44721359550f, CG3 = 0.37796447301f;
    float acc[8] = {};
    __shared__ int eL[64];
    __shared__ int sL[64];
    __shared__ float yL[64][17];
    for (int base = lo; base < hi; base += 64) {
        int cnt = min(64, hi - base);
        for (int i = t; i < cnt; i += 256) {
            int e = perm[base + i];
            eL[i] = e;
            sL[i] = eidx[e];
        }
        __syncthreads();
        for (int i = t; i < cnt * 16; i += 256) {
            int el = i >> 4, m = i & 15;
            yL[el][m] = ea[(size_t)eL[el] * 16 + m];
        }
        __syncthreads();
        for (int j = 0; j < cnt; j++) {
            int e = eL[j];
            if (e < eLo || e >= eHi) continue;
            const float* tw = tp_w + (size_t)(e - eLo) * 512;
            float xs = xup[(size_t)sL[j] * 128 + c];
            const float* y = yL[j];
            if (half == 0) {
                float u0 = tw[c] * xs;
                float u1 = tw[128 + c] * xs * CG1;
                float u2 = tw[256 + c] * xs * CG2;
                acc[0] = fmaf(u0, y[0], acc[0]);
                #pragma unroll
                for (int m = 0; m < 3; m++) acc[1 + m] = fmaf(u1, y[1 + m], acc[1 + m]);
                #pragma unroll
                for (int m = 0; m < 4; m++) acc[4 + m] = fmaf(u2, y[4 + m], acc[4 + m]);
            } else {
                float u2 = tw[256 + c] * xs * CG2;
                float u3 = tw[384 + c] * xs * CG3;
                acc[0] = fmaf(u2, y[8], acc[0]);
                #pragma unroll
                for (int m = 0; m < 7; m++) acc[1 + m] = fmaf(u3, y[9 + m], acc[1 + m]);
            }
        }
        __syncthreads();
    }
    float* mrow = msg + (size_t)n * 2048;
    if (storeMode) {
        if (half == 0) {
            mrow[c] = acc[0];
            #pragma unroll
            for (int m = 0; m < 3; m++) mrow[128 + c * 3 + m] = acc[1 + m];
            #pragma unroll
            for (int m = 0; m < 4; m++) mrow[512 + c * 5 + m] = acc[4 + m];
        } else {
            mrow[512 + c * 5 + 4] = acc[0];
            #pragma unroll
            for (int m = 0; m < 7; m++) mrow[1152 + c * 7 + m] = acc[1 + m];
        }
    } else {
        if (half == 0) {
            mrow[c] += acc[0];
            #pragma unroll
            for (int m = 0; m < 3; m++) mrow[128 + c * 3 + m] += acc[1 + m];
            #pragma unroll
            for (int m = 0; m < 4; m++) mrow[512 + c * 5 + m] += acc[4 + m];
        } else {
            mrow[512 + c * 5 + 4] += acc[0];
            #pragma unroll
            for (int m = 0; m < 7; m++) mrow[1152 + c * 7 + m] += acc[1 + m];
        }
    }
}

// ---------------- K4: in-place per-node W_out transform ------------------------
__global__ __launch_bounds__(128) void k_out(
    float* __restrict__ buf, const float* __restrict__ Wout, int N)
{
    __shared__ float ms[8][2056];
    const int t = threadIdx.x;
    const int n0 = blockIdx.x * 8;
    for (int i = t; i < 8 * 512; i += 128) {
        int rr = i >> 9, c4 = i & 511;
        int n = n0 + rr;
        float4 v = make_float4(0.f, 0.f, 0.f, 0.f);
        if (n < N) v = ((const float4*)(buf + (size_t)n * 2048))[c4];
        ((float4*)&ms[rr][0])[c4] = v;
    }
    __syncthreads();
    const int tk = t & 15, tn = t >> 4;
    const int n = n0 + tn;
    float acc[8][16] = {};
    for (int c = 0; c < 128; c++) {
        float mv[16];
        mv[0] = ms[tn][c];
        #pragma unroll
        for (int m = 0; m < 3; m++) mv[1 + m] = ms[tn][128 + c * 3 + m];
        #pragma unroll
        for (int m = 0; m < 5; m++) mv[4 + m] = ms[tn][512 + c * 5 + m];
        #pragma unroll
        for (int m = 0; m < 7; m++) mv[9 + m] = ms[tn][1152 + c * 7 + m];
        #pragma unroll
        for (int i = 0; i < 8; i++) {
            const int k = tk + 16 * i;
            const float w0 = Wout[(size_t)c * 128 + k];
            const float w1 = Wout[16384 + (size_t)c * 128 + k];
            const float w2 = Wout[32768 + (size_t)c * 128 + k];
            const float w3 = Wout[49152 + (size_t)c * 128 + k];
            acc[i][0] = fmaf(w0, mv[0], acc[i][0]);
            #pragma unroll
            for (int m = 0; m < 3; m++) acc[i][1 + m] = fmaf(w1, mv[1 + m], acc[i][1 + m]);
            #pragma unroll
            for (int m = 0; m < 5; m++) acc[i][4 + m] = fmaf(w2, mv[4 + m], acc[i][4 + m]);
            #pragma unroll
            for (int m = 0; m < 7; m++) acc[i][9 + m] = fmaf(w3, mv[9 + m], acc[i][9 + m]);
        }
    }
    if (n < N) {
        #pragma unroll
        for (int i = 0; i < 8; i++) {
            const int k = tk + 16 * i;
            float* op = buf + (size_t)n * 2048 + k * 16;
            #pragma unroll
            for (int q = 0; q < 4; q++) {
                float4 v = make_float4(acc[i][q * 4 + 0] * 0.1f, acc[i][q * 4 + 1] * 0.1f,
                                       acc[i][q * 4 + 2] * 0.1f, acc[i][q * 4 + 3] * 0.1f);
                *(float4*)(op + q * 4) = v;
            }
        }
    }
}

extern "C" void kernel_launch(void* const* d_in, const int* in_sizes, int n_in,
                              void* d_out, int out_size, void* d_ws, size_t ws_size,
                              hipStream_t stream)
{
    const float* node_feats = (const float*)d_in[1];
    const float* edge_attrs = (const float*)d_in[2];
    const float* edge_feats = (const float*)d_in[3];
    const int*   edge_index = (const int*)d_in[4];
    const float* W_up   = (const float*)d_in[5];
    const float* W_down = (const float*)d_in[6];
    const float* W_skip = (const float*)d_in[7];
    const float* W_fc0  = (const float*)d_in[8];
    const float* W_fc1  = (const float*)d_in[9];
    const float* W_fc2  = (const float*)d_in[10];
    const float* W_fc3  = (const float*)d_in[11];
    const float* W_out  = (const float*)d_in[12];
    const int N = in_sizes[1] / 128;
    const int E = in_sizes[3] / 8;

    float* out = (float*)d_out;                  // first N*2048 floats: message -> out (in place)
    float* sc  = out + (size_t)N * 2048;

    // workspace layout
    float* xup   = (float*)d_ws;
    float* xdown = xup + (size_t)N * 128;
    int* deg    = (int*)(xdown + (size_t)N * 64);
    int* fill   = deg + N;
    int* rowptr = fill + N;
    int* perm   = rowptr + N + 1;
    size_t used = (size_t)((char*)(perm + E) - (char*)d_ws);
    used = (used + 255) & ~(size_t)255;
    float* tp_w = (float*)((char*)d_ws + used);
    size_t avail = (ws_size > used) ? ws_size - used : 0;
    long long Ec_l = (long long)(avail / (512 * sizeof(float)));
    int Ec = (int)(Ec_l > E ? E : Ec_l);
    if (Ec < 1) Ec = 1;
    const int nchunks = (E + Ec - 1) / Ec;

    hipMemsetAsync(deg, 0, (size_t)2 * N * sizeof(int), stream);   // deg + fill
    if (nchunks > 1)
        hipMemsetAsync(out, 0, (size_t)N * 2048 * sizeof(float), stream);

    dim3 g1((N + 63) / 64, 5);
    k_node_gemm<<<g1, 256, 0, stream>>>(node_feats, W_skip, W_up, W_down, sc, xup, xdown, N);

    const int* recv = edge_index + E;
    k_hist<<<(E + 255) / 256, 256, 0, stream>>>(recv, deg, E);
    k_scan<<<1, 1024, 0, stream>>>(deg, rowptr, N);
    k_scatter<<<(E + 255) / 256, 256, 0, stream>>>(recv, rowptr, fill, perm, E);
    k_sortlists<<<(N + 255) / 256, 256, 0, stream>>>(perm, rowptr, N);

    for (int ch = 0; ch < nchunks; ch++) {
        int eLo = ch * Ec;
        int eHi = eLo + Ec; if (eHi > E) eHi = E;
        int nE = eHi - eLo;
        k_mlp<<<(nE + EB - 1) / EB, 256, 0, stream>>>(edge_feats, edge_index, xdown,
                                                      W_fc0, W_fc1, W_fc2, W_fc3,
                                                      tp_w, E, eLo, eHi);
        k_gather<<<N, 256, 0, stream>>>(tp_w, xup, edge_attrs, edge_index, perm, rowptr,
                                        out, E, eLo, eHi, nchunks == 1 ? 1 : 0);
    }

    k_out<<<(N + 7) / 8, 128, 0, stream>>>(out, W_out, N);
}

// Round 3
// 571.908 us; speedup vs baseline: 19.1441x; 2.5112x over previous
//
#include <hip/hip_runtime.h>
#include <math.h>

using bf16x8 = __attribute__((ext_vector_type(8))) short;
using f32x4  = __attribute__((ext_vector_type(4))) float;

__device__ __forceinline__ float silu_f(float x) { return x / (1.0f + expf(-x)); }

__device__ __forceinline__ unsigned short f2bf(float x) {
    union { float f; unsigned u; } v; v.f = x;
    unsigned u = v.u;
    return (unsigned short)((u + 0x7FFFu + ((u >> 16) & 1u)) >> 16);
}
__device__ __forceinline__ float bf2f(unsigned short h) {
    union { unsigned u; float f; } v; v.u = ((unsigned)h) << 16;
    return v.f;
}

// ---------------- K1: node GEMM: sc = A@Wskip, xup = A@Wup, xdown = A@Wdown ----
__global__ __launch_bounds__(256) void k_node_gemm(
    const float* __restrict__ A,
    const float* __restrict__ Wskip, const float* __restrict__ Wup, const float* __restrict__ Wdown,
    float* __restrict__ sc, float* __restrict__ xup, float* __restrict__ xdown, int N)
{
    __shared__ float As[64][129];
    const int t = threadIdx.x;
    const int n0 = blockIdx.x * 64;
    for (int i = t; i < 64 * 32; i += 256) {
        int r = i >> 5, c4 = i & 31;
        int n = n0 + r;
        float4 v = make_float4(0.f, 0.f, 0.f, 0.f);
        if (n < N) v = ((const float4*)(A + (size_t)n * 128))[c4];
        As[r][c4 * 4 + 0] = v.x; As[r][c4 * 4 + 1] = v.y;
        As[r][c4 * 4 + 2] = v.z; As[r][c4 * 4 + 3] = v.w;
    }
    __syncthreads();
    const int tc = t & 15, tr = t >> 4;
    const int col0 = blockIdx.y * 64 + tc * 4;   // global col in [0, 320)
    const float* W; float* dst; int ldw, wc, ldd;
    if (col0 < 128)      { W = Wskip; ldw = 128; wc = col0;       dst = sc;    ldd = 128; }
    else if (col0 < 256) { W = Wup;   ldw = 128; wc = col0 - 128; dst = xup;   ldd = 128; }
    else                 { W = Wdown; ldw = 64;  wc = col0 - 256; dst = xdown; ldd = 64;  }
    float acc[4][4] = {};
    for (int k = 0; k < 128; k++) {
        float4 wv = *(const float4*)(W + (size_t)k * ldw + wc);
        float wvv[4] = {wv.x, wv.y, wv.z, wv.w};
        float av[4];
        #pragma unroll
        for (int ii = 0; ii < 4; ii++) av[ii] = As[tr * 4 + ii][k];
        #pragma unroll
        for (int ii = 0; ii < 4; ii++)
            #pragma unroll
            for (int jj = 0; jj < 4; jj++)
                acc[ii][jj] = fmaf(av[ii], wvv[jj], acc[ii][jj]);
    }
    #pragma unroll
    for (int ii = 0; ii < 4; ii++) {
        int n = n0 + tr * 4 + ii;
        if (n < N)
            *(float4*)(dst + (size_t)n * ldd + wc) =
                make_float4(acc[ii][0], acc[ii][1], acc[ii][2], acc[ii][3]);
    }
}

// ---------------- weight prep: fold scale, transpose to [n][k], bf16, pad K ----
__global__ __launch_bounds__(256) void k_prep_w(
    const float* __restrict__ W, unsigned short* __restrict__ Wt,
    int Kin, int Kpad, int Nout, float scale)
{
    int i = blockIdx.x * 256 + threadIdx.x;
    if (i >= Nout * Kpad) return;
    int n = i / Kpad, k = i - n * Kpad;
    float v = (k < Kin) ? W[(size_t)k * Nout + n] * scale : 0.f;
    Wt[i] = f2bf(v);
}

// ---------------- K2: edge MLP via bf16 MFMA ----------------------------------
#define MEB 64

template<int KSTEPS, int KPADW, bool SILU>
__device__ __forceinline__ void mlp_layer(
    const unsigned short (*in)[264], unsigned short (*out)[264],
    const unsigned short* __restrict__ Wt, int w, int lane)
{
    f32x4 acc[4][4];
    #pragma unroll
    for (int mt = 0; mt < 4; mt++)
        #pragma unroll
        for (int nt = 0; nt < 4; nt++)
            acc[mt][nt] = (f32x4){0.f, 0.f, 0.f, 0.f};
    const int rA = lane & 15;
    const int kb = (lane >> 4) * 8;
    #pragma unroll
    for (int ks = 0; ks < KSTEPS; ks++) {
        const int kk = ks * 32 + kb;
        bf16x8 a[4], b[4];
        #pragma unroll
        for (int mt = 0; mt < 4; mt++)
            a[mt] = *(const bf16x8*)&in[mt * 16 + rA][kk];
        #pragma unroll
        for (int nt = 0; nt < 4; nt++)
            b[nt] = *(const bf16x8*)&Wt[(size_t)(w * 64 + nt * 16 + rA) * KPADW + kk];
        #pragma unroll
        for (int mt = 0; mt < 4; mt++)
            #pragma unroll
            for (int nt = 0; nt < 4; nt++)
                acc[mt][nt] = __builtin_amdgcn_mfma_f32_16x16x32_bf16(a[mt], b[nt], acc[mt][nt], 0, 0, 0);
    }
    const int r0 = (lane >> 4) * 4;
    #pragma unroll
    for (int mt = 0; mt < 4; mt++)
        #pragma unroll
        for (int nt = 0; nt < 4; nt++) {
            const int col = w * 64 + nt * 16 + rA;
            #pragma unroll
            for (int r = 0; r < 4; r++) {
                float x = acc[mt][nt][r];
                if (SILU) x = silu_f(x);
                out[mt * 16 + r0 + r][col] = f2bf(x);
            }
        }
}

__global__ __launch_bounds__(256, 2) void k_mlp_mfma(
    const float* __restrict__ ef, const int* __restrict__ eidx,
    const float* __restrict__ xdown,
    const unsigned short* __restrict__ Wt0, const unsigned short* __restrict__ Wt1,
    const unsigned short* __restrict__ Wt2, const unsigned short* __restrict__ Wt3,
    unsigned short* __restrict__ tp_w, int E, int eLo, int eHi)
{
    __shared__ unsigned short bufA[MEB][264];
    __shared__ unsigned short bufB[MEB][264];
    __shared__ int sE[MEB], rE[MEB];
    const int t = threadIdx.x;
    const int w = t >> 6, lane = t & 63;
    const int e0 = eLo + blockIdx.x * MEB;
    if (t < MEB) {
        int e = e0 + t; if (e >= E) e = E - 1;
        sE[t] = eidx[e]; rE[t] = eidx[E + e];
    }
    __syncthreads();
    // zero K-pad cols 136..159 (avoid NaN garbage * 0 issues)
    for (int i = t; i < MEB * 24; i += 256) {
        int r = i / 24, c = 136 + i % 24;
        bufA[r][c] = 0;
    }
    // stage aug = [ef(8) | xdown[s](64) | xdown[r](64)] as bf16
    for (int i = t; i < MEB * 34; i += 256) {
        int e = i / 34, j = i - e * 34;
        float4 v;
        if (j < 2) { int ee = e0 + e; if (ee >= E) ee = E - 1; v = ((const float4*)(ef + (size_t)ee * 8))[j]; }
        else if (j < 18) v = ((const float4*)(xdown + (size_t)sE[e] * 64))[j - 2];
        else             v = ((const float4*)(xdown + (size_t)rE[e] * 64))[j - 18];
        ushort4 h;
        h.x = f2bf(v.x); h.y = f2bf(v.y); h.z = f2bf(v.z); h.w = f2bf(v.w);
        *(ushort4*)&bufA[e][j * 4] = h;
    }
    __syncthreads();

    mlp_layer<5, 160, true>(bufA, bufB, Wt0, w, lane);
    __syncthreads();
    mlp_layer<8, 256, true>(bufB, bufA, Wt1, w, lane);
    __syncthreads();
    mlp_layer<8, 256, true>(bufA, bufB, Wt2, w, lane);
    __syncthreads();

    for (int p = 0; p < 2; p++) {
        mlp_layer<8, 256, false>(bufB, bufA, Wt3 + (size_t)p * 256 * 256, w, lane);
        __syncthreads();
        for (int i = t; i < MEB * 64; i += 256) {
            int r = i >> 6, c4 = i & 63;
            int ee = e0 + r;
            if (ee < eHi) {
                ushort4 hv = *(ushort4*)&bufA[r][c4 * 4];
                *(ushort4*)&tp_w[(size_t)(ee - eLo) * 512 + p * 256 + c4 * 4] = hv;
            }
        }
        __syncthreads();
    }
}

// ---------------- CSR construction --------------------------------------------
__global__ __launch_bounds__(256) void k_hist(const int* __restrict__ recv, int* __restrict__ deg, int E)
{
    int e = blockIdx.x * 256 + threadIdx.x;
    if (e < E) atomicAdd(&deg[recv[e]], 1);
}

__global__ __launch_bounds__(1024) void k_scan(const int* __restrict__ deg, int* __restrict__ rowptr, int N)
{
    __shared__ int sdata[1024];
    __shared__ int carry;
    const int t = threadIdx.x;
    if (t == 0) carry = 0;
    __syncthreads();
    for (int base = 0; base < N; base += 1024) {
        int i = base + t;
        int v = (i < N) ? deg[i] : 0;
        sdata[t] = v;
        __syncthreads();
        for (int off = 1; off < 1024; off <<= 1) {
            int x = (t >= off) ? sdata[t - off] : 0;
            __syncthreads();
            sdata[t] += x;
            __syncthreads();
        }
        if (i < N) rowptr[i] = carry + sdata[t] - v;
        __syncthreads();
        if (t == 0) carry += sdata[1023];
        __syncthreads();
    }
    if (t == 0) rowptr[N] = carry;
}

__global__ __launch_bounds__(256) void k_scatter(const int* __restrict__ recv,
    const int* __restrict__ rowptr, int* __restrict__ fill, int* __restrict__ perm, int E)
{
    int e = blockIdx.x * 256 + threadIdx.x;
    if (e < E) {
        int r = recv[e];
        int pos = rowptr[r] + atomicAdd(&fill[r], 1);
        perm[pos] = e;
    }
}

__global__ __launch_bounds__(256) void k_sortlists(int* __restrict__ perm, const int* __restrict__ rowptr, int N)
{
    int n = blockIdx.x * 256 + threadIdx.x;
    if (n >= N) return;
    int lo = rowptr[n], hi = rowptr[n + 1];
    for (int i = lo + 1; i < hi; i++) {
        int key = perm[i];
        int j = i - 1;
        while (j >= lo && perm[j] > key) { perm[j + 1] = perm[j]; j--; }
        perm[j + 1] = key;
    }
}

// ---------------- K3: per-node gather + tensor product ------------------------
__global__ __launch_bounds__(256) void k_gather(
    const unsigned short* __restrict__ tp_w, const float* __restrict__ xup, const float* __restrict__ ea,
    const int* __restrict__ eidx, const int* __restrict__ perm, const int* __restrict__ rowptr,
    float* __restrict__ msg, int E, int eLo, int eHi, int storeMode)
{
    const int n = blockIdx.x;
    const int lo = rowptr[n], hi = rowptr[n + 1];
    const int t = threadIdx.x;
    const int c = t & 127, half = t >> 7;
    constexpr float CG1 = 0.57735026919f, CG2 = 0.44721359550f, CG3 = 0.37796447301f;
    float acc[8] = {};
    __shared__ int eL[64];
    __shared__ int sL[64];
    __shared__ float yL[64][17];
    for (int base = lo; base < hi; base += 64) {
        int cnt = min(64, hi - base);
        for (int i = t; i < cnt; i += 256) {
            int e = perm[base + i];
            eL[i] = e;
            sL[i] = eidx[e];
        }
        __syncthreads();
        for (int i = t; i < cnt * 16; i += 256) {
            int el = i >> 4, m = i & 15;
            yL[el][m] = ea[(size_t)eL[el] * 16 + m];
        }
        __syncthreads();
        for (int j = 0; j < cnt; j++) {
            int e = eL[j];
            if (e < eLo || e >= eHi) continue;
            const unsigned short* tw = tp_w + (size_t)(e - eLo) * 512;
            float xs = xup[(size_t)sL[j] * 128 + c];
            const float* y = yL[j];
            if (half == 0) {
                float u0 = bf2f(tw[c]) * xs;
                float u1 = bf2f(tw[128 + c]) * xs * CG1;
                float u2 = bf2f(tw[256 + c]) * xs * CG2;
                acc[0] = fmaf(u0, y[0], acc[0]);
                #pragma unroll
                for (int m = 0; m < 3; m++) acc[1 + m] = fmaf(u1, y[1 + m], acc[1 + m]);
                #pragma unroll
                for (int m = 0; m < 4; m++) acc[4 + m] = fmaf(u2, y[4 + m], acc[4 + m]);
            } else {
                float u2 = bf2f(tw[256 + c]) * xs * CG2;
                float u3 = bf2f(tw[384 + c]) * xs * CG3;
                acc[0] = fmaf(u2, y[8], acc[0]);
                #pragma unroll
                for (int m = 0; m < 7; m++) acc[1 + m] = fmaf(u3, y[9 + m], acc[1 + m]);
            }
        }
        __syncthreads();
    }
    float* mrow = msg + (size_t)n * 2048;
    if (storeMode) {
        if (half == 0) {
            mrow[c] = acc[0];
            #pragma unroll
            for (int m = 0; m < 3; m++) mrow[128 + c * 3 + m] = acc[1 + m];
            #pragma unroll
            for (int m = 0; m < 4; m++) mrow[512 + c * 5 + m] = acc[4 + m];
        } else {
            mrow[512 + c * 5 + 4] = acc[0];
            #pragma unroll
            for (int m = 0; m < 7; m++) mrow[1152 + c * 7 + m] = acc[1 + m];
        }
    } else {
        if (half == 0) {
            mrow[c] += acc[0];
            #pragma unroll
            for (int m = 0; m < 3; m++) mrow[128 + c * 3 + m] += acc[1 + m];
            #pragma unroll
            for (int m = 0; m < 4; m++) mrow[512 + c * 5 + m] += acc[4 + m];
        } else {
            mrow[512 + c * 5 + 4] += acc[0];
            #pragma unroll
            for (int m = 0; m < 7; m++) mrow[1152 + c * 7 + m] += acc[1 + m];
        }
    }
}

// ---------------- K4: in-place per-node W_out transform ------------------------
__global__ __launch_bounds__(128) void k_out(
    float* __restrict__ buf, const float* __restrict__ Wout, int N)
{
    __shared__ float ms[8][2056];
    const int t = threadIdx.x;
    const int n0 = blockIdx.x * 8;
    for (int i = t; i < 8 * 512; i += 128) {
        int rr = i >> 9, c4 = i & 511;
        int n = n0 + rr;
        float4 v = make_float4(0.f, 0.f, 0.f, 0.f);
        if (n < N) v = ((const float4*)(buf + (size_t)n * 2048))[c4];
        ((float4*)&ms[rr][0])[c4] = v;
    }
    __syncthreads();
    const int tk = t & 15, tn = t >> 4;
    const int n = n0 + tn;
    float acc[8][16] = {};
    for (int c = 0; c < 128; c++) {
        float mv[16];
        mv[0] = ms[tn][c];
        #pragma unroll
        for (int m = 0; m < 3; m++) mv[1 + m] = ms[tn][128 + c * 3 + m];
        #pragma unroll
        for (int m = 0; m < 5; m++) mv[4 + m] = ms[tn][512 + c * 5 + m];
        #pragma unroll
        for (int m = 0; m < 7; m++) mv[9 + m] = ms[tn][1152 + c * 7 + m];
        #pragma unroll
        for (int i = 0; i < 8; i++) {
            const int k = tk + 16 * i;
            const float w0 = Wout[(size_t)c * 128 + k];
            const float w1 = Wout[16384 + (size_t)c * 128 + k];
            const float w2 = Wout[32768 + (size_t)c * 128 + k];
            const float w3 = Wout[49152 + (size_t)c * 128 + k];
            acc[i][0] = fmaf(w0, mv[0], acc[i][0]);
            #pragma unroll
            for (int m = 0; m < 3; m++) acc[i][1 + m] = fmaf(w1, mv[1 + m], acc[i][1 + m]);
            #pragma unroll
            for (int m = 0; m < 5; m++) acc[i][4 + m] = fmaf(w2, mv[4 + m], acc[i][4 + m]);
            #pragma unroll
            for (int m = 0; m < 7; m++) acc[i][9 + m] = fmaf(w3, mv[9 + m], acc[i][9 + m]);
        }
    }
    if (n < N) {
        #pragma unroll
        for (int i = 0; i < 8; i++) {
            const int k = tk + 16 * i;
            float* op = buf + (size_t)n * 2048 + k * 16;
            #pragma unroll
            for (int q = 0; q < 4; q++) {
                float4 v = make_float4(acc[i][q * 4 + 0] * 0.1f, acc[i][q * 4 + 1] * 0.1f,
                                       acc[i][q * 4 + 2] * 0.1f, acc[i][q * 4 + 3] * 0.1f);
                *(float4*)(op + q * 4) = v;
            }
        }
    }
}

extern "C" void kernel_launch(void* const* d_in, const int* in_sizes, int n_in,
                              void* d_out, int out_size, void* d_ws, size_t ws_size,
                              hipStream_t stream)
{
    const float* node_feats = (const float*)d_in[1];
    const float* edge_attrs = (const float*)d_in[2];
    const float* edge_feats = (const float*)d_in[3];
    const int*   edge_index = (const int*)d_in[4];
    const float* W_up   = (const float*)d_in[5];
    const float* W_down = (const float*)d_in[6];
    const float* W_skip = (const float*)d_in[7];
    const float* W_fc0  = (const float*)d_in[8];
    const float* W_fc1  = (const float*)d_in[9];
    const float* W_fc2  = (const float*)d_in[10];
    const float* W_fc3  = (const float*)d_in[11];
    const float* W_out  = (const float*)d_in[12];
    const int N = in_sizes[1] / 128;
    const int E = in_sizes[3] / 8;

    float* out = (float*)d_out;                  // first N*2048 floats: message -> out (in place)
    float* sc  = out + (size_t)N * 2048;

    // workspace layout
    float* xup   = (float*)d_ws;
    float* xdown = xup + (size_t)N * 128;
    int* deg    = (int*)(xdown + (size_t)N * 64);
    int* fill   = deg + N;
    int* rowptr = fill + N;
    int* perm   = rowptr + N + 1;
    size_t used = (size_t)((char*)(perm + E) - (char*)d_ws);
    used = (used + 255) & ~(size_t)255;
    unsigned short* Wt0 = (unsigned short*)((char*)d_ws + used);
    unsigned short* Wt1 = Wt0 + 256 * 160;
    unsigned short* Wt2 = Wt1 + 256 * 256;
    unsigned short* Wt3 = Wt2 + 256 * 256;
    used = (size_t)((char*)(Wt3 + 512 * 256) - (char*)d_ws);
    used = (used + 255) & ~(size_t)255;
    unsigned short* tp_w = (unsigned short*)((char*)d_ws + used);
    size_t avail = (ws_size > used) ? ws_size - used : 0;
    long long Ec_l = (long long)(avail / (512 * sizeof(unsigned short)));
    int Ec = (int)(Ec_l > E ? E : Ec_l);
    if (Ec < 1) Ec = 1;
    const int nchunks = (E + Ec - 1) / Ec;

    hipMemsetAsync(deg, 0, (size_t)2 * N * sizeof(int), stream);   // deg + fill
    if (nchunks > 1)
        hipMemsetAsync(out, 0, (size_t)N * 2048 * sizeof(float), stream);

    dim3 g1((N + 63) / 64, 5);
    k_node_gemm<<<g1, 256, 0, stream>>>(node_feats, W_skip, W_up, W_down, sc, xup, xdown, N);

    constexpr float S0 = 0.085749292571254f; // 1/sqrt(136)
    k_prep_w<<<(256 * 160 + 255) / 256, 256, 0, stream>>>(W_fc0, Wt0, 136, 160, 256, S0);
    k_prep_w<<<(256 * 256 + 255) / 256, 256, 0, stream>>>(W_fc1, Wt1, 256, 256, 256, 0.0625f);
    k_prep_w<<<(256 * 256 + 255) / 256, 256, 0, stream>>>(W_fc2, Wt2, 256, 256, 256, 0.0625f);
    k_prep_w<<<(512 * 256 + 255) / 256, 256, 0, stream>>>(W_fc3, Wt3, 256, 256, 512, 0.0625f);

    const int* recv = edge_index + E;
    k_hist<<<(E + 255) / 256, 256, 0, stream>>>(recv, deg, E);
    k_scan<<<1, 1024, 0, stream>>>(deg, rowptr, N);
    k_scatter<<<(E + 255) / 256, 256, 0, stream>>>(recv, rowptr, fill, perm, E);
    k_sortlists<<<(N + 255) / 256, 256, 0, stream>>>(perm, rowptr, N);

    for (int ch = 0; ch < nchunks; ch++) {
        int eLo = ch * Ec;
        int eHi = eLo + Ec; if (eHi > E) eHi = E;
        int nE = eHi - eLo;
        k_mlp_mfma<<<(nE + MEB - 1) / MEB, 256, 0, stream>>>(edge_feats, edge_index, xdown,
                                                             Wt0, Wt1, Wt2, Wt3,
                                                             tp_w, E, eLo, eHi);
        k_gather<<<N, 256, 0, stream>>>(tp_w, xup, edge_attrs, edge_index, perm, rowptr,
                                        out, E, eLo, eHi, nchunks == 1 ? 1 : 0);
    }

    k_out<<<(N + 7) / 8, 128, 0, stream>>>(out, W_out, N);
}

// Round 4
// 416.619 us; speedup vs baseline: 26.2798x; 1.3727x over previous
//
#include <hip/hip_runtime.h>
#include <math.h>

using bf16x8 = __attribute__((ext_vector_type(8))) short;
using f32x4  = __attribute__((ext_vector_type(4))) float;

__device__ __forceinline__ float silu_f(float x) { return x / (1.0f + expf(-x)); }

__device__ __forceinline__ unsigned short f2bf(float x) {
    union { float f; unsigned u; } v; v.f = x;
    unsigned u = v.u;
    return (unsigned short)((u + 0x7FFFu + ((u >> 16) & 1u)) >> 16);
}
__device__ __forceinline__ float bf2f(unsigned short h) {
    union { unsigned u; float f; } v; v.u = ((unsigned)h) << 16;
    return v.f;
}

// ---------------- K1: node GEMM: sc = A@Wskip, xup = A@Wup, xdown = A@Wdown ----
__global__ __launch_bounds__(256) void k_node_gemm(
    const float* __restrict__ A,
    const float* __restrict__ Wskip, const float* __restrict__ Wup, const float* __restrict__ Wdown,
    float* __restrict__ sc, float* __restrict__ xup, float* __restrict__ xdown, int N)
{
    __shared__ float As[64][129];
    const int t = threadIdx.x;
    const int n0 = blockIdx.x * 64;
    for (int i = t; i < 64 * 32; i += 256) {
        int r = i >> 5, c4 = i & 31;
        int n = n0 + r;
        float4 v = make_float4(0.f, 0.f, 0.f, 0.f);
        if (n < N) v = ((const float4*)(A + (size_t)n * 128))[c4];
        As[r][c4 * 4 + 0] = v.x; As[r][c4 * 4 + 1] = v.y;
        As[r][c4 * 4 + 2] = v.z; As[r][c4 * 4 + 3] = v.w;
    }
    __syncthreads();
    const int tc = t & 15, tr = t >> 4;
    const int col0 = blockIdx.y * 64 + tc * 4;   // global col in [0, 320)
    const float* W; float* dst; int ldw, wc, ldd;
    if (col0 < 128)      { W = Wskip; ldw = 128; wc = col0;       dst = sc;    ldd = 128; }
    else if (col0 < 256) { W = Wup;   ldw = 128; wc = col0 - 128; dst = xup;   ldd = 128; }
    else                 { W = Wdown; ldw = 64;  wc = col0 - 256; dst = xdown; ldd = 64;  }
    float acc[4][4] = {};
    for (int k = 0; k < 128; k++) {
        float4 wv = *(const float4*)(W + (size_t)k * ldw + wc);
        float wvv[4] = {wv.x, wv.y, wv.z, wv.w};
        float av[4];
        #pragma unroll
        for (int ii = 0; ii < 4; ii++) av[ii] = As[tr * 4 + ii][k];
        #pragma unroll
        for (int ii = 0; ii < 4; ii++)
            #pragma unroll
            for (int jj = 0; jj < 4; jj++)
                acc[ii][jj] = fmaf(av[ii], wvv[jj], acc[ii][jj]);
    }
    #pragma unroll
    for (int ii = 0; ii < 4; ii++) {
        int n = n0 + tr * 4 + ii;
        if (n < N)
            *(float4*)(dst + (size_t)n * ldd + wc) =
                make_float4(acc[ii][0], acc[ii][1], acc[ii][2], acc[ii][3]);
    }
}

// ---------------- weight prep: fold scale, transpose to [n][k], bf16, pad K ----
__global__ __launch_bounds__(256) void k_prep_w(
    const float* __restrict__ W, unsigned short* __restrict__ Wt,
    int Kin, int Kpad, int Nout, float scale)
{
    int i = blockIdx.x * 256 + threadIdx.x;
    if (i >= Nout * Kpad) return;
    int n = i / Kpad, k = i - n * Kpad;
    float v = (k < Kin) ? W[(size_t)k * Nout + n] * scale : 0.f;
    Wt[i] = f2bf(v);
}

// ---------------- K2: edge MLP + xup-mult + W_out GEMM -> z --------------------
#define MEB 64

template<int KSTEPS, int KPADW, bool SILU>
__device__ __forceinline__ void mlp_layer(
    const unsigned short (*in)[264], unsigned short (*out)[264],
    const unsigned short* __restrict__ Wt, int w, int lane)
{
    f32x4 acc[4][4];
    #pragma unroll
    for (int mt = 0; mt < 4; mt++)
        #pragma unroll
        for (int nt = 0; nt < 4; nt++)
            acc[mt][nt] = (f32x4){0.f, 0.f, 0.f, 0.f};
    const int rA = lane & 15;
    const int kb = (lane >> 4) * 8;
    #pragma unroll
    for (int ks = 0; ks < KSTEPS; ks++) {
        const int kk = ks * 32 + kb;
        bf16x8 a[4], b[4];
        #pragma unroll
        for (int mt = 0; mt < 4; mt++)
            a[mt] = *(const bf16x8*)&in[mt * 16 + rA][kk];
        #pragma unroll
        for (int nt = 0; nt < 4; nt++)
            b[nt] = *(const bf16x8*)&Wt[(size_t)(w * 64 + nt * 16 + rA) * KPADW + kk];
        #pragma unroll
        for (int mt = 0; mt < 4; mt++)
            #pragma unroll
            for (int nt = 0; nt < 4; nt++)
                acc[mt][nt] = __builtin_amdgcn_mfma_f32_16x16x32_bf16(a[mt], b[nt], acc[mt][nt], 0, 0, 0);
    }
    const int r0 = (lane >> 4) * 4;
    #pragma unroll
    for (int mt = 0; mt < 4; mt++)
        #pragma unroll
        for (int nt = 0; nt < 4; nt++) {
            const int col = w * 64 + nt * 16 + rA;
            #pragma unroll
            for (int r = 0; r < 4; r++) {
                float x = acc[mt][nt][r];
                if (SILU) x = silu_f(x);
                out[mt * 16 + r0 + r][col] = f2bf(x);
            }
        }
}

__global__ __launch_bounds__(256, 2) void k_mlp_mfma(
    const float* __restrict__ ef, const int* __restrict__ eidx,
    const float* __restrict__ xdown, const float* __restrict__ xup,
    const unsigned short* __restrict__ Wt0, const unsigned short* __restrict__ Wt1,
    const unsigned short* __restrict__ Wt2, const unsigned short* __restrict__ Wt3,
    const unsigned short* __restrict__ WoT,
    unsigned short* __restrict__ z, int E, int eLo, int eHi)
{
    __shared__ unsigned short bufA[MEB][264];
    __shared__ unsigned short bufB[MEB][264];
    __shared__ int sE[MEB], rE[MEB];
    const int t = threadIdx.x;
    const int w = t >> 6, lane = t & 63;
    const int e0 = eLo + blockIdx.x * MEB;
    if (t < MEB) {
        int e = e0 + t; if (e >= E) e = E - 1;
        sE[t] = eidx[e]; rE[t] = eidx[E + e];
    }
    __syncthreads();
    // zero K-pad cols 136..159
    for (int i = t; i < MEB * 24; i += 256) {
        int r = i / 24, c = 136 + i % 24;
        bufA[r][c] = 0;
    }
    // stage aug = [ef(8) | xdown[s](64) | xdown[r](64)] as bf16
    for (int i = t; i < MEB * 34; i += 256) {
        int e = i / 34, j = i - e * 34;
        float4 v;
        if (j < 2) { int ee = e0 + e; if (ee >= E) ee = E - 1; v = ((const float4*)(ef + (size_t)ee * 8))[j]; }
        else if (j < 18) v = ((const float4*)(xdown + (size_t)sE[e] * 64))[j - 2];
        else             v = ((const float4*)(xdown + (size_t)rE[e] * 64))[j - 18];
        ushort4 h;
        h.x = f2bf(v.x); h.y = f2bf(v.y); h.z = f2bf(v.z); h.w = f2bf(v.w);
        *(ushort4*)&bufA[e][j * 4] = h;
    }
    __syncthreads();

    mlp_layer<5, 160, true>(bufA, bufB, Wt0, w, lane);
    __syncthreads();
    mlp_layer<8, 256, true>(bufB, bufA, Wt1, w, lane);
    __syncthreads();
    mlp_layer<8, 256, true>(bufA, bufB, Wt2, w, lane);
    __syncthreads();

    const int rA = lane & 15;
    const int kb = (lane >> 4) * 8;
    const int r0 = (lane >> 4) * 4;
    const int l_loc = w >> 1;
    const int kbase = (w & 1) * 64;

    for (int p = 0; p < 2; p++) {
        // tp_w cols [p*256, p*256+256) -> bufA[e][0..255]
        mlp_layer<8, 256, false>(bufB, bufA, Wt3 + (size_t)p * 256 * 256, w, lane);
        __syncthreads();
        // multiply xup[sender] into tpw (in place, bf16)
        for (int i = t; i < MEB * 256; i += 256) {
            int e = i >> 8, jh = i & 255;
            int c = jh & 127;
            float v = bf2f(bufA[e][jh]) * xup[(size_t)sE[e] * 128 + c];
            bufA[e][jh] = f2bf(v);
        }
        __syncthreads();
        // z-GEMM: z[e, l*128+k] = sum_c u[e, l_loc*128+c] * W_out[l][c,k]*0.1
        const int l = p * 2 + l_loc;
        f32x4 acc[4][4];
        #pragma unroll
        for (int mt = 0; mt < 4; mt++)
            #pragma unroll
            for (int nt = 0; nt < 4; nt++)
                acc[mt][nt] = (f32x4){0.f, 0.f, 0.f, 0.f};
        #pragma unroll
        for (int ks = 0; ks < 4; ks++) {
            const int kk = ks * 32 + kb;
            bf16x8 a[4], b[4];
            #pragma unroll
            for (int mt = 0; mt < 4; mt++)
                a[mt] = *(const bf16x8*)&bufA[mt * 16 + rA][l_loc * 128 + kk];
            #pragma unroll
            for (int nt = 0; nt < 4; nt++)
                b[nt] = *(const bf16x8*)&WoT[(size_t)(l * 128 + kbase + nt * 16 + rA) * 128 + kk];
            #pragma unroll
            for (int mt = 0; mt < 4; mt++)
                #pragma unroll
                for (int nt = 0; nt < 4; nt++)
                    acc[mt][nt] = __builtin_amdgcn_mfma_f32_16x16x32_bf16(a[mt], b[nt], acc[mt][nt], 0, 0, 0);
        }
        __syncthreads();   // all reads of u done before overwrite
        #pragma unroll
        for (int mt = 0; mt < 4; mt++)
            #pragma unroll
            for (int nt = 0; nt < 4; nt++)
                #pragma unroll
                for (int r = 0; r < 4; r++)
                    bufA[mt * 16 + r0 + r][l_loc * 128 + kbase + nt * 16 + rA] = f2bf(acc[mt][nt][r]);
        __syncthreads();
        // coalesced store of z half p
        for (int i = t; i < MEB * 64; i += 256) {
            int r = i >> 6, c4 = i & 63;
            int ee = e0 + r;
            if (ee < eHi) {
                ushort4 hv = *(ushort4*)&bufA[r][c4 * 4];
                *(ushort4*)&z[(size_t)(ee - eLo) * 512 + p * 256 + c4 * 4] = hv;
            }
        }
        __syncthreads();
    }
}

// ---------------- CSR construction --------------------------------------------
__global__ __launch_bounds__(256) void k_hist(const int* __restrict__ recv, int* __restrict__ deg, int E)
{
    int e = blockIdx.x * 256 + threadIdx.x;
    if (e < E) atomicAdd(&deg[recv[e]], 1);
}

__global__ __launch_bounds__(1024) void k_scan(const int* __restrict__ deg, int* __restrict__ rowptr, int N)
{
    __shared__ int sdata[1024];
    __shared__ int carry;
    const int t = threadIdx.x;
    if (t == 0) carry = 0;
    __syncthreads();
    for (int base = 0; base < N; base += 1024) {
        int i = base + t;
        int v = (i < N) ? deg[i] : 0;
        sdata[t] = v;
        __syncthreads();
        for (int off = 1; off < 1024; off <<= 1) {
            int x = (t >= off) ? sdata[t - off] : 0;
            __syncthreads();
            sdata[t] += x;
            __syncthreads();
        }
        if (i < N) rowptr[i] = carry + sdata[t] - v;
        __syncthreads();
        if (t == 0) carry += sdata[1023];
        __syncthreads();
    }
    if (t == 0) rowptr[N] = carry;
}

__global__ __launch_bounds__(256) void k_scatter(const int* __restrict__ recv,
    const int* __restrict__ rowptr, int* __restrict__ fill, int* __restrict__ perm, int E)
{
    int e = blockIdx.x * 256 + threadIdx.x;
    if (e < E) {
        int r = recv[e];
        int pos = rowptr[r] + atomicAdd(&fill[r], 1);
        perm[pos] = e;
    }
}

__global__ __launch_bounds__(256) void k_sortlists(int* __restrict__ perm, const int* __restrict__ rowptr, int N)
{
    int n = blockIdx.x * 256 + threadIdx.x;
    if (n >= N) return;
    int lo = rowptr[n], hi = rowptr[n + 1];
    for (int i = lo + 1; i < hi; i++) {
        int key = perm[i];
        int j = i - 1;
        while (j >= lo && perm[j] > key) { perm[j + 1] = perm[j]; j--; }
        perm[j + 1] = key;
    }
}

// ---------------- K3: per-node gather: out[n,k*16+j] = sum_e z*Y*cg ------------
__global__ __launch_bounds__(256) void k_gather(
    const unsigned short* __restrict__ z, const float* __restrict__ ea,
    const int* __restrict__ perm, const int* __restrict__ rowptr,
    float* __restrict__ outb, int E, int eLo, int eHi, int storeMode)
{
    const int n = blockIdx.x;
    const int lo = rowptr[n], hi = rowptr[n + 1];
    const int t = threadIdx.x;
    const int c = t & 127, half = t >> 7;
    constexpr float CG1 = 0.57735026919f, CG2 = 0.44721359550f, CG3 = 0.37796447301f;
    float acc[8] = {};
    __shared__ int eL[64];
    __shared__ float yL[64][17];
    for (int base = lo; base < hi; base += 64) {
        int cnt = min(64, hi - base);
        for (int i = t; i < cnt; i += 256)
            eL[i] = perm[base + i];
        __syncthreads();
        for (int i = t; i < cnt * 16; i += 256) {
            int el = i >> 4, m = i & 15;
            yL[el][m] = ea[(size_t)eL[el] * 16 + m];
        }
        __syncthreads();
        for (int j = 0; j < cnt; j++) {
            int e = eL[j];
            if (e < eLo || e >= eHi) continue;
            const unsigned short* zz = z + (size_t)(e - eLo) * 512;
            const float* y = yL[j];
            if (half == 0) {
                float z0 = bf2f(zz[c]);
                float z1 = bf2f(zz[128 + c]) * CG1;
                float z2 = bf2f(zz[256 + c]) * CG2;
                acc[0] = fmaf(z0, y[0], acc[0]);
                #pragma unroll
                for (int m = 0; m < 3; m++) acc[1 + m] = fmaf(z1, y[1 + m], acc[1 + m]);
                #pragma unroll
                for (int m = 0; m < 4; m++) acc[4 + m] = fmaf(z2, y[4 + m], acc[4 + m]);
            } else {
                float z2 = bf2f(zz[256 + c]) * CG2;
                float z3 = bf2f(zz[384 + c]) * CG3;
                acc[0] = fmaf(z2, y[8], acc[0]);
                #pragma unroll
                for (int m = 0; m < 7; m++) acc[1 + m] = fmaf(z3, y[9 + m], acc[1 + m]);
            }
        }
        __syncthreads();
    }
    float* orow = outb + (size_t)n * 2048 + (size_t)c * 16 + half * 8;
    if (storeMode) {
        *(float4*)orow       = make_float4(acc[0], acc[1], acc[2], acc[3]);
        *(float4*)(orow + 4) = make_float4(acc[4], acc[5], acc[6], acc[7]);
    } else {
        float4 a = *(float4*)orow, b = *(float4*)(orow + 4);
        a.x += acc[0]; a.y += acc[1]; a.z += acc[2]; a.w += acc[3];
        b.x += acc[4]; b.y += acc[5]; b.z += acc[6]; b.w += acc[7];
        *(float4*)orow = a; *(float4*)(orow + 4) = b;
    }
}

extern "C" void kernel_launch(void* const* d_in, const int* in_sizes, int n_in,
                              void* d_out, int out_size, void* d_ws, size_t ws_size,
                              hipStream_t stream)
{
    const float* node_feats = (const float*)d_in[1];
    const float* edge_attrs = (const float*)d_in[2];
    const float* edge_feats = (const float*)d_in[3];
    const int*   edge_index = (const int*)d_in[4];
    const float* W_up   = (const float*)d_in[5];
    const float* W_down = (const float*)d_in[6];
    const float* W_skip = (const float*)d_in[7];
    const float* W_fc0  = (const float*)d_in[8];
    const float* W_fc1  = (const float*)d_in[9];
    const float* W_fc2  = (const float*)d_in[10];
    const float* W_fc3  = (const float*)d_in[11];
    const float* W_out  = (const float*)d_in[12];
    const int N = in_sizes[1] / 128;
    const int E = in_sizes[3] / 8;

    float* out = (float*)d_out;                  // first N*2048 floats: final out
    float* sc  = out + (size_t)N * 2048;

    // workspace layout
    float* xup   = (float*)d_ws;
    float* xdown = xup + (size_t)N * 128;
    int* deg    = (int*)(xdown + (size_t)N * 64);
    int* fill   = deg + N;
    int* rowptr = fill + N;
    int* perm   = rowptr + N + 1;
    size_t used = (size_t)((char*)(perm + E) - (char*)d_ws);
    used = (used + 255) & ~(size_t)255;
    unsigned short* Wt0 = (unsigned short*)((char*)d_ws + used);
    unsigned short* Wt1 = Wt0 + 256 * 160;
    unsigned short* Wt2 = Wt1 + 256 * 256;
    unsigned short* Wt3 = Wt2 + 256 * 256;
    unsigned short* WoT = Wt3 + 512 * 256;       // [l][k][c] bf16, 0.1 folded
    used = (size_t)((char*)(WoT + 4 * 128 * 128) - (char*)d_ws);
    used = (used + 255) & ~(size_t)255;
    unsigned short* zbuf = (unsigned short*)((char*)d_ws + used);
    size_t avail = (ws_size > used) ? ws_size - used : 0;
    long long Ec_l = (long long)(avail / (512 * sizeof(unsigned short)));
    int Ec = (int)(Ec_l > E ? E : Ec_l);
    if (Ec < 1) Ec = 1;
    const int nchunks = (E + Ec - 1) / Ec;

    hipMemsetAsync(deg, 0, (size_t)2 * N * sizeof(int), stream);   // deg + fill
    if (nchunks > 1)
        hipMemsetAsync(out, 0, (size_t)N * 2048 * sizeof(float), stream);

    dim3 g1((N + 63) / 64, 5);
    k_node_gemm<<<g1, 256, 0, stream>>>(node_feats, W_skip, W_up, W_down, sc, xup, xdown, N);

    constexpr float S0 = 0.085749292571254f; // 1/sqrt(136)
    k_prep_w<<<(256 * 160 + 255) / 256, 256, 0, stream>>>(W_fc0, Wt0, 136, 160, 256, S0);
    k_prep_w<<<(256 * 256 + 255) / 256, 256, 0, stream>>>(W_fc1, Wt1, 256, 256, 256, 0.0625f);
    k_prep_w<<<(256 * 256 + 255) / 256, 256, 0, stream>>>(W_fc2, Wt2, 256, 256, 256, 0.0625f);
    k_prep_w<<<(512 * 256 + 255) / 256, 256, 0, stream>>>(W_fc3, Wt3, 256, 256, 512, 0.0625f);
    for (int l = 0; l < 4; l++)
        k_prep_w<<<(128 * 128 + 255) / 256, 256, 0, stream>>>(W_out + (size_t)l * 16384,
                                                              WoT + (size_t)l * 16384,
                                                              128, 128, 128, 0.1f);

    const int* recv = edge_index + E;
    k_hist<<<(E + 255) / 256, 256, 0, stream>>>(recv, deg, E);
    k_scan<<<1, 1024, 0, stream>>>(deg, rowptr, N);
    k_scatter<<<(E + 255) / 256, 256, 0, stream>>>(recv, rowptr, fill, perm, E);
    k_sortlists<<<(N + 255) / 256, 256, 0, stream>>>(perm, rowptr, N);

    for (int ch = 0; ch < nchunks; ch++) {
        int eLo = ch * Ec;
        int eHi = eLo + Ec; if (eHi > E) eHi = E;
        int nE = eHi - eLo;
        k_mlp_mfma<<<(nE + MEB - 1) / MEB, 256, 0, stream>>>(edge_feats, edge_index, xdown, xup,
                                                             Wt0, Wt1, Wt2, Wt3, WoT,
                                                             zbuf, E, eLo, eHi);
        k_gather<<<N, 256, 0, stream>>>(zbuf, edge_attrs, perm, rowptr,
                                        out, E, eLo, eHi, nchunks == 1 ? 1 : 0);
    }
}